// Round 1
// baseline (646.034 us; speedup 1.0000x reference)
//
#include <hip/hip_runtime.h>

#define EF 128
#define KNN 8

// Kernel 1: Y1[n][d] = b1[d] + sum_k input[n][k] * W1[k][d]
// (b1 folded here; xyz part of layer-1 handled per-edge in edge_kernel)
__global__ __launch_bounds__(256) void y1_kernel(const float* __restrict__ input,
                                                 const float* __restrict__ W1,
                                                 const float* __restrict__ b1,
                                                 float* __restrict__ Y1, int npts) {
    __shared__ float in_lds[2][EF];
    int local = threadIdx.x / EF;   // 0..1  (2 points per block)
    int d     = threadIdx.x % EF;
    int p     = blockIdx.x * 2 + local;
    if (p < npts) in_lds[local][d] = input[p * EF + d];
    __syncthreads();
    if (p >= npts) return;
    float acc = b1[d];
#pragma unroll 4
    for (int k = 0; k < EF; ++k) {
        acc = fmaf(in_lds[local][k], W1[k * EF + d], acc);
    }
    Y1[p * EF + d] = acc;
}

// Kernel 2: per point p (one 128-thread block): 8 edges ->
//   h1[e][d] = leaky( Y1[idx_e][d] + xyz_e . W1[128..130][d] (+ b1 if !PRE) )
//   h2[e][d] = b2[d] + sum_k h1[e][k] * W2[k][d]
//   out[p][d] = max_e h2[e][d]
template <bool PRE>
__global__ __launch_bounds__(128) void edge_kernel(
    const float* __restrict__ input,    // [N][128] (used if !PRE)
    const float* __restrict__ Y1,       // [N][128] (used if PRE)
    const int*   __restrict__ knn_idx,  // [N*8]
    const float* __restrict__ knn_xyz,  // [N*8][3]
    const float* __restrict__ W1,       // [131][128] row-major
    const float* __restrict__ b1,       // [128]
    const float* __restrict__ W2,       // [128][128] row-major
    const float* __restrict__ b2,       // [128]
    float* __restrict__ out, int npts)
{
    __shared__ float h1T[EF][KNN];   // transposed: layer-2 reads h1T[k][0..7] = b128 broadcast
    __shared__ float g_lds[EF];      // staging for gathered input row (!PRE only)

    int p = blockIdx.x;
    int d = threadIdx.x;             // 0..127

    // per-thread xyz weights (rows 128..130 of W1)
    float wx = W1[(EF + 0) * EF + d];
    float wy = W1[(EF + 1) * EF + d];
    float wz = W1[(EF + 2) * EF + d];

    for (int e = 0; e < KNN; ++e) {
        int   ofs = p * KNN + e;
        int   idx = knn_idx[ofs];
        float x = knn_xyz[ofs * 3 + 0];
        float y = knn_xyz[ofs * 3 + 1];
        float z = knn_xyz[ofs * 3 + 2];
        float h;
        if (PRE) {
            h = Y1[(size_t)idx * EF + d];          // b1 already folded
        } else {
            __syncthreads();                        // protect g_lds reuse
            g_lds[d] = input[(size_t)idx * EF + d];
            __syncthreads();
            h = b1[d];
#pragma unroll 4
            for (int k = 0; k < EF; ++k) h = fmaf(g_lds[k], W1[k * EF + d], h);
        }
        h = fmaf(x, wx, h);
        h = fmaf(y, wy, h);
        h = fmaf(z, wz, h);
        h = (h >= 0.f) ? h : 0.01f * h;            // leaky_relu(0.01)
        h1T[d][e] = h;
    }
    __syncthreads();

    // layer 2, register-tiled: thread d computes h2[e][d] for all 8 edges
    float bb2 = b2[d];
    float acc[KNN];
#pragma unroll
    for (int e = 0; e < KNN; ++e) acc[e] = bb2;

#pragma unroll 4
    for (int k = 0; k < EF; ++k) {
        float w = W2[k * EF + d];                  // coalesced, L1/L2-resident
#pragma unroll
        for (int e = 0; e < KNN; ++e)
            acc[e] = fmaf(h1T[k][e], w, acc[e]);   // b128 broadcast reads
    }

    float m = acc[0];
#pragma unroll
    for (int e = 1; e < KNN; ++e) m = fmaxf(m, acc[e]);
    out[p * EF + d] = m;
}

extern "C" void kernel_launch(void* const* d_in, const int* in_sizes, int n_in,
                              void* d_out, int out_size, void* d_ws, size_t ws_size,
                              hipStream_t stream) {
    const float* input   = (const float*)d_in[0];
    const int*   knn_idx = (const int*)  d_in[1];
    const float* knn_xyz = (const float*)d_in[2];
    const float* W1      = (const float*)d_in[3];
    const float* b1      = (const float*)d_in[4];
    const float* W2      = (const float*)d_in[5];
    const float* b2      = (const float*)d_in[6];
    float*       out     = (float*)d_out;

    int npts = in_sizes[0] / EF;                    // 100000
    size_t need = (size_t)npts * EF * sizeof(float);

    if (ws_size >= need) {
        float* Y1 = (float*)d_ws;
        y1_kernel<<<(npts + 1) / 2, 256, 0, stream>>>(input, W1, b1, Y1, npts);
        edge_kernel<true><<<npts, 128, 0, stream>>>(input, Y1, knn_idx, knn_xyz,
                                                    W1, b1, W2, b2, out, npts);
    } else {
        edge_kernel<false><<<npts, 128, 0, stream>>>(input, nullptr, knn_idx, knn_xyz,
                                                     W1, b1, W2, b2, out, npts);
    }
}

// Round 2
// 137.861 us; speedup vs baseline: 4.6861x; 4.6861x over previous
//
#include <hip/hip_runtime.h>

#define EF 128
#define KNN 8

typedef __attribute__((ext_vector_type(8)))  short          short8;
typedef __attribute__((ext_vector_type(8)))  unsigned short ushort8;
typedef __attribute__((ext_vector_type(16))) float          f32x16;

static __device__ __forceinline__ float bf2f(unsigned short u) {
    union { unsigned int i; float f; } v;
    v.i = ((unsigned int)u) << 16;
    return v.f;
}
// round-to-nearest-even f32 -> bf16 bits (finite inputs only)
static __device__ __forceinline__ unsigned short f2bf(float f) {
    unsigned int x = __float_as_uint(f);
    unsigned int r = x + 0x7fffu + ((x >> 16) & 1u);
    return (unsigned short)(r >> 16);
}

// ---------------------------------------------------------------------------
// pack_kernel: W1[:128] and W2 -> MFMA-B-fragment-ordered bf16; W1[128:131]
// -> bf16 [3][128]. Fragment order for 32x32x16: lane l supplies
// B[k = kt*16 + (l>>5)*8 + j][n = nt*32 + (l&31)], linear index
// (((kt*4+nt)*64 + l)*8 + j).
// ---------------------------------------------------------------------------
__global__ __launch_bounds__(256) void pack_kernel(
    const float* __restrict__ W1, const float* __restrict__ W2,
    unsigned short* __restrict__ W1p, unsigned short* __restrict__ W2p,
    unsigned short* __restrict__ Wxyz)
{
    int t = blockIdx.x * 256 + threadIdx.x;
    if (t < 2 * 16384) {
        int m = t >> 14;            // 0: W1, 1: W2
        int s = t & 16383;
        int j  = s & 7;
        int l  = (s >> 3) & 63;
        int nt = (s >> 9) & 3;
        int kt = (s >> 11) & 7;
        int k = kt * 16 + (l >> 5) * 8 + j;
        int n = nt * 32 + (l & 31);
        const float* W = m ? W2 : W1;
        unsigned short* P = m ? W2p : W1p;
        P[s] = f2bf(W[k * EF + n]);
    } else if (t < 2 * 16384 + 3 * EF) {
        int s = t - 2 * 16384;
        Wxyz[s] = f2bf(W1[(EF + (s >> 7)) * EF + (s & 127)]);
    }
}

// ---------------------------------------------------------------------------
// zgemm_kernel: Z[p][d] = bf16( b1[d] + sum_k input[p][k] * W1[k][d] )
// One wave per 32-point tile; N=128 in 4 tiles of 32; K=128 in 8 tiles of 16.
// ---------------------------------------------------------------------------
__global__ __launch_bounds__(256) void zgemm_kernel(
    const float* __restrict__ input,
    const unsigned short* __restrict__ W1p,
    const float* __restrict__ b1,
    unsigned short* __restrict__ Z,
    int npts, int ntiles)
{
    int l = threadIdx.x & 63;
    int tile = blockIdx.x * 4 + (threadIdx.x >> 6);
    if (tile >= ntiles) return;
    int p0   = tile * 32;
    int r    = l & 31;
    int half = l >> 5;
    int prow = p0 + r;
    if (prow >= npts) prow = npts - 1;      // clamp for ragged tail (reads only)
    const float* Arow = input + (size_t)prow * EF;

    f32x16 acc[4];
#pragma unroll
    for (int nt = 0; nt < 4; ++nt)
#pragma unroll
        for (int i = 0; i < 16; ++i) acc[nt][i] = 0.f;

    for (int kt = 0; kt < 8; ++kt) {
        int k0 = kt * 16 + half * 8;
        float4 a0 = *(const float4*)(Arow + k0);
        float4 a1 = *(const float4*)(Arow + k0 + 4);
        short8 a;
        a[0] = (short)f2bf(a0.x); a[1] = (short)f2bf(a0.y);
        a[2] = (short)f2bf(a0.z); a[3] = (short)f2bf(a0.w);
        a[4] = (short)f2bf(a1.x); a[5] = (short)f2bf(a1.y);
        a[6] = (short)f2bf(a1.z); a[7] = (short)f2bf(a1.w);
#pragma unroll
        for (int nt = 0; nt < 4; ++nt) {
            short8 b = *(const short8*)(W1p + ((size_t)((kt * 4 + nt) * 64 + l)) * 8);
            acc[nt] = __builtin_amdgcn_mfma_f32_32x32x16_bf16(a, b, acc[nt], 0, 0, 0);
        }
    }

    int col = l & 31;
#pragma unroll
    for (int nt = 0; nt < 4; ++nt) {
        float bb = b1[nt * 32 + col];
#pragma unroll
        for (int reg = 0; reg < 16; ++reg) {
            int row = (reg & 3) + 8 * (reg >> 2) + 4 * half;
            int p = p0 + row;
            if (p < npts)
                Z[(size_t)p * EF + nt * 32 + col] = f2bf(acc[nt][reg] + bb);
        }
    }
}

// ---------------------------------------------------------------------------
// edge_mfma_kernel: per wave a 32-edge tile (= 4 points).
//   h1[e][d] = leaky( Z[idx_e][d] + xyz_e . Wxyz[:,d] )   (A fragment, bf16)
//   h2 = h1 @ W2 (MFMA, fp32 acc) ; out[p][d] = max_e h2 + b2[d]
// ---------------------------------------------------------------------------
__global__ __launch_bounds__(256) void edge_mfma_kernel(
    const unsigned short* __restrict__ Z,
    const int* __restrict__ knn_idx,
    const float* __restrict__ knn_xyz,
    const unsigned short* __restrict__ W2p,
    const unsigned short* __restrict__ Wxyz,
    const float* __restrict__ b2,
    float* __restrict__ out,
    int npts, int nedges, int ntiles)
{
    int l = threadIdx.x & 63;
    int tile = blockIdx.x * 4 + (threadIdx.x >> 6);
    if (tile >= ntiles) return;
    int E0   = tile * 32;
    int r    = l & 31;
    int half = l >> 5;
    int edge = E0 + r;
    if (edge >= nedges) edge = nedges - 1;  // clamp (reads only)

    int   idx = knn_idx[edge];
    float x = knn_xyz[edge * 3 + 0];
    float y = knn_xyz[edge * 3 + 1];
    float z = knn_xyz[edge * 3 + 2];
    const unsigned short* Zrow = Z + (size_t)idx * EF;

    f32x16 acc[4];
#pragma unroll
    for (int nt = 0; nt < 4; ++nt)
#pragma unroll
        for (int i = 0; i < 16; ++i) acc[nt][i] = 0.f;

    for (int kt = 0; kt < 8; ++kt) {
        int d0 = kt * 16 + half * 8;
        ushort8 zv  = *(const ushort8*)(Zrow + d0);
        ushort8 wxv = *(const ushort8*)(Wxyz + 0 * EF + d0);
        ushort8 wyv = *(const ushort8*)(Wxyz + 1 * EF + d0);
        ushort8 wzv = *(const ushort8*)(Wxyz + 2 * EF + d0);
        short8 a;
#pragma unroll
        for (int j = 0; j < 8; ++j) {
            float h = bf2f(zv[j]);
            h = fmaf(x, bf2f(wxv[j]), h);
            h = fmaf(y, bf2f(wyv[j]), h);
            h = fmaf(z, bf2f(wzv[j]), h);
            h = (h > 0.f) ? h : 0.01f * h;         // leaky_relu
            a[j] = (short)f2bf(h);
        }
#pragma unroll
        for (int nt = 0; nt < 4; ++nt) {
            short8 b = *(const short8*)(W2p + ((size_t)((kt * 4 + nt) * 64 + l)) * 8);
            acc[nt] = __builtin_amdgcn_mfma_f32_32x32x16_bf16(a, b, acc[nt], 0, 0, 0);
        }
    }

    // max over 8 edge-rows per point, +b2, store
    int col = l & 31;
    int p0  = tile * 4;
#pragma unroll
    for (int nt = 0; nt < 4; ++nt) {
#pragma unroll
        for (int P = 0; P < 4; ++P) {
            // this lane's regs 4P..4P+3 hold rows 8P + (0..3) + 4*half
            float m = fmaxf(fmaxf(acc[nt][4 * P + 0], acc[nt][4 * P + 1]),
                            fmaxf(acc[nt][4 * P + 2], acc[nt][4 * P + 3]));
            m = fmaxf(m, __shfl_xor(m, 32));       // combine the two halves
            int p = p0 + P;
            if (half == 0 && p < npts)
                out[(size_t)p * EF + nt * 32 + col] = m + b2[nt * 32 + col];
        }
    }
}

extern "C" void kernel_launch(void* const* d_in, const int* in_sizes, int n_in,
                              void* d_out, int out_size, void* d_ws, size_t ws_size,
                              hipStream_t stream) {
    const float* input   = (const float*)d_in[0];
    const int*   knn_idx = (const int*)  d_in[1];
    const float* knn_xyz = (const float*)d_in[2];
    const float* W1      = (const float*)d_in[3];
    const float* b1      = (const float*)d_in[4];
    const float* W2      = (const float*)d_in[5];
    const float* b2      = (const float*)d_in[6];
    float*       out     = (float*)d_out;

    int npts   = in_sizes[0] / EF;          // 100000
    int nedges = in_sizes[1];               // npts * 8

    // workspace layout
    unsigned short* W1p  = (unsigned short*)d_ws;                  // 16384
    unsigned short* W2p  = W1p + 16384;                            // 16384
    unsigned short* Wxyz = W2p + 16384;                            // 384
    unsigned short* Z    = (unsigned short*)((char*)d_ws + 66560); // npts*128

    pack_kernel<<<(2 * 16384 + 3 * EF + 255) / 256, 256, 0, stream>>>(
        W1, W2, W1p, W2p, Wxyz);

    int ztiles = (npts + 31) / 32;
    zgemm_kernel<<<(ztiles + 3) / 4, 256, 0, stream>>>(
        input, W1p, b1, Z, npts, ztiles);

    int etiles = (nedges + 31) / 32;
    edge_mfma_kernel<<<(etiles + 3) / 4, 256, 0, stream>>>(
        Z, knn_idx, knn_xyz, W2p, Wxyz, b2, out, npts, nedges, etiles);
}

// Round 5
// 133.964 us; speedup vs baseline: 4.8224x; 1.0291x over previous
//
#include <hip/hip_runtime.h>
#include <hip/hip_bf16.h>

#define EF 128
#define KNN 8

typedef __attribute__((ext_vector_type(8)))  short          short8;
typedef __attribute__((ext_vector_type(8)))  unsigned short ushort8;
typedef __attribute__((ext_vector_type(16))) float          f32x16;

// software round-to-nearest-even f32 -> bf16 bits (cold paths)
static __device__ __forceinline__ unsigned short f2bf(float f) {
    unsigned int x = __float_as_uint(f);
    unsigned int r = x + 0x7fffu + ((x >> 16) & 1u);
    return (unsigned short)(r >> 16);
}
// sanctioned compiler conversion (RNE) for hot paths
static __device__ __forceinline__ short f2bf_hw(float f) {
    return (short)__bfloat16_as_ushort(__float2bfloat16(f));
}

// ---------------------------------------------------------------------------
// pack_kernel: W1[:128] and W2 -> MFMA-B-fragment-ordered bf16.
// Fragment order for 32x32x16: lane l supplies
// B[k = kt*16 + (l>>5)*8 + j][n = nt*32 + (l&31)], linear index
// (((kt*4+nt)*64 + l)*8 + j).
// ---------------------------------------------------------------------------
__global__ __launch_bounds__(256) void pack_kernel(
    const float* __restrict__ W1, const float* __restrict__ W2,
    unsigned short* __restrict__ W1p, unsigned short* __restrict__ W2p)
{
    int t = blockIdx.x * 256 + threadIdx.x;
    if (t < 2 * 16384) {
        int m = t >> 14;            // 0: W1, 1: W2
        int s = t & 16383;
        int j  = s & 7;
        int l  = (s >> 3) & 63;
        int nt = (s >> 9) & 3;
        int kt = (s >> 11) & 7;
        int k = kt * 16 + (l >> 5) * 8 + j;
        int n = nt * 32 + (l & 31);
        const float* W = m ? W2 : W1;
        unsigned short* P = m ? W2p : W1p;
        P[s] = f2bf(W[k * EF + n]);
    }
}

// ---------------------------------------------------------------------------
// zgemm_kernel: Z[p][d] = bf16( b1[d] + sum_k input[p][k] * W1[k][d] )
// One wave per 32-point tile; N=128 in 4 tiles of 32; K=128 in 8 tiles of 16.
// ---------------------------------------------------------------------------
__global__ __launch_bounds__(256) void zgemm_kernel(
    const float* __restrict__ input,
    const unsigned short* __restrict__ W1p,
    const float* __restrict__ b1,
    unsigned short* __restrict__ Z,
    int npts, int ntiles)
{
    int l = threadIdx.x & 63;
    int tile = blockIdx.x * 4 + (threadIdx.x >> 6);
    if (tile >= ntiles) return;
    int p0   = tile * 32;
    int r    = l & 31;
    int half = l >> 5;
    int prow = p0 + r;
    if (prow >= npts) prow = npts - 1;      // clamp for ragged tail (reads only)
    const float* Arow = input + (size_t)prow * EF;

    f32x16 acc[4];
#pragma unroll
    for (int nt = 0; nt < 4; ++nt)
#pragma unroll
        for (int i = 0; i < 16; ++i) acc[nt][i] = 0.f;

#pragma unroll
    for (int kt = 0; kt < 8; ++kt) {
        int k0 = kt * 16 + half * 8;
        float4 a0 = *(const float4*)(Arow + k0);
        float4 a1 = *(const float4*)(Arow + k0 + 4);
        short8 a;
        a[0] = f2bf_hw(a0.x); a[1] = f2bf_hw(a0.y);
        a[2] = f2bf_hw(a0.z); a[3] = f2bf_hw(a0.w);
        a[4] = f2bf_hw(a1.x); a[5] = f2bf_hw(a1.y);
        a[6] = f2bf_hw(a1.z); a[7] = f2bf_hw(a1.w);
#pragma unroll
        for (int nt = 0; nt < 4; ++nt) {
            short8 b = *(const short8*)(W1p + ((size_t)((kt * 4 + nt) * 64 + l)) * 8);
            acc[nt] = __builtin_amdgcn_mfma_f32_32x32x16_bf16(a, b, acc[nt], 0, 0, 0);
        }
    }

    int col = l & 31;
#pragma unroll
    for (int nt = 0; nt < 4; ++nt) {
        float bb = b1[nt * 32 + col];
#pragma unroll
        for (int reg = 0; reg < 16; ++reg) {
            int row = (reg & 3) + 8 * (reg >> 2) + 4 * half;
            int p = p0 + row;
            if (p < npts)
                Z[(size_t)p * EF + nt * 32 + col] = f2bf(acc[nt][reg] + bb);
        }
    }
}

// ---------------------------------------------------------------------------
// edge_mfma_kernel: per wave a 32-edge tile (= 4 points).
//   h1[e][d] = leaky( Z[idx_e][d] + xyz_e . W1[128:131][d] )   (A frag, bf16)
//   h2 = h1 @ W2 (MFMA, fp32 acc) ; out[p][d] = max_e h2 + b2[d]
// ---------------------------------------------------------------------------
__global__ __launch_bounds__(256) void edge_mfma_kernel(
    const unsigned short* __restrict__ Z,
    const int* __restrict__ knn_idx,
    const float* __restrict__ knn_xyz,
    const unsigned short* __restrict__ W2p,
    const float* __restrict__ W1,       // xyz rows read at +128*EF (f32)
    const float* __restrict__ b2,
    float* __restrict__ out,
    int npts, int nedges, int ntiles)
{
    int l = threadIdx.x & 63;
    int tile = blockIdx.x * 4 + (threadIdx.x >> 6);
    if (tile >= ntiles) return;
    int E0   = tile * 32;
    int r    = l & 31;
    int half = l >> 5;
    int edge = E0 + r;
    if (edge >= nedges) edge = nedges - 1;  // clamp (reads only)

    int   idx = knn_idx[edge];
    float x = knn_xyz[edge * 3 + 0];
    float y = knn_xyz[edge * 3 + 1];
    float z = knn_xyz[edge * 3 + 2];
    const unsigned short* Zrow = Z + (size_t)idx * EF;
    const float* W1x = W1 + EF * EF;        // rows 128..130, f32

    f32x16 acc[4];
#pragma unroll
    for (int nt = 0; nt < 4; ++nt)
#pragma unroll
        for (int i = 0; i < 16; ++i) acc[nt][i] = 0.f;

#pragma unroll
    for (int kt = 0; kt < 8; ++kt) {
        int d0 = kt * 16 + half * 8;
        ushort8 zv = *(const ushort8*)(Zrow + d0);
        float4 wx0 = *(const float4*)(W1x + 0 * EF + d0);
        float4 wx1 = *(const float4*)(W1x + 0 * EF + d0 + 4);
        float4 wy0 = *(const float4*)(W1x + 1 * EF + d0);
        float4 wy1 = *(const float4*)(W1x + 1 * EF + d0 + 4);
        float4 wz0 = *(const float4*)(W1x + 2 * EF + d0);
        float4 wz1 = *(const float4*)(W1x + 2 * EF + d0 + 4);
        float wxa[8] = {wx0.x, wx0.y, wx0.z, wx0.w, wx1.x, wx1.y, wx1.z, wx1.w};
        float wya[8] = {wy0.x, wy0.y, wy0.z, wy0.w, wy1.x, wy1.y, wy1.z, wy1.w};
        float wza[8] = {wz0.x, wz0.y, wz0.z, wz0.w, wz1.x, wz1.y, wz1.z, wz1.w};

        short8 a;
#pragma unroll
        for (int j = 0; j < 8; ++j) {
            float h = __uint_as_float(((unsigned int)zv[j]) << 16);  // bf16 -> f32
            h = fmaf(x, wxa[j], h);
            h = fmaf(y, wya[j], h);
            h = fmaf(z, wza[j], h);
            h = fmaxf(h, 0.01f * h);        // leaky_relu, exact both signs
            a[j] = f2bf_hw(h);
        }
#pragma unroll
        for (int nt = 0; nt < 4; ++nt) {
            short8 b = *(const short8*)(W2p + ((size_t)((kt * 4 + nt) * 64 + l)) * 8);
            acc[nt] = __builtin_amdgcn_mfma_f32_32x32x16_bf16(a, b, acc[nt], 0, 0, 0);
        }
    }

    // max over 8 edge-rows per point, +b2, store
    int col = l & 31;
    int p0  = tile * 4;
#pragma unroll
    for (int nt = 0; nt < 4; ++nt) {
#pragma unroll
        for (int P = 0; P < 4; ++P) {
            float m = fmaxf(fmaxf(acc[nt][4 * P + 0], acc[nt][4 * P + 1]),
                            fmaxf(acc[nt][4 * P + 2], acc[nt][4 * P + 3]));
            m = fmaxf(m, __shfl_xor(m, 32));       // combine the two halves
            int p = p0 + P;
            if (half == 0 && p < npts)
                out[(size_t)p * EF + nt * 32 + col] = m + b2[nt * 32 + col];
        }
    }
}

extern "C" void kernel_launch(void* const* d_in, const int* in_sizes, int n_in,
                              void* d_out, int out_size, void* d_ws, size_t ws_size,
                              hipStream_t stream) {
    const float* input   = (const float*)d_in[0];
    const int*   knn_idx = (const int*)  d_in[1];
    const float* knn_xyz = (const float*)d_in[2];
    const float* W1      = (const float*)d_in[3];
    const float* b1      = (const float*)d_in[4];
    const float* W2      = (const float*)d_in[5];
    const float* b2      = (const float*)d_in[6];
    float*       out     = (float*)d_out;

    int npts   = in_sizes[0] / EF;          // 100000
    int nedges = in_sizes[1];               // npts * 8

    // workspace layout
    unsigned short* W1p = (unsigned short*)d_ws;                  // 16384
    unsigned short* W2p = W1p + 16384;                            // 16384
    unsigned short* Z   = (unsigned short*)((char*)d_ws + 65536); // npts*128

    pack_kernel<<<128, 256, 0, stream>>>(W1, W2, W1p, W2p);

    int ztiles = (npts + 31) / 32;
    zgemm_kernel<<<(ztiles + 3) / 4, 256, 0, stream>>>(
        input, W1p, b1, Z, npts, ztiles);

    int etiles = (nedges + 31) / 32;
    edge_mfma_kernel<<<(etiles + 3) / 4, 256, 0, stream>>>(
        Z, knn_idx, knn_xyz, W2p, W1, b2, out, npts, nedges, etiles);
}

// Round 7
// 128.377 us; speedup vs baseline: 5.0323x; 1.0435x over previous
//
#include <hip/hip_runtime.h>
#include <hip/hip_bf16.h>

#define EF 128
#define KNN 8

typedef __attribute__((ext_vector_type(8)))  short          short8;
typedef __attribute__((ext_vector_type(8)))  unsigned short ushort8;
typedef __attribute__((ext_vector_type(4)))  float          f32x4;
typedef __attribute__((ext_vector_type(16))) float          f32x16;

// software round-to-nearest-even f32 -> bf16 bits (cold paths)
static __device__ __forceinline__ unsigned short f2bf(float f) {
    unsigned int x = __float_as_uint(f);
    unsigned int r = x + 0x7fffu + ((x >> 16) & 1u);
    return (unsigned short)(r >> 16);
}
// sanctioned compiler conversion (RNE) for hot paths
static __device__ __forceinline__ short f2bf_hw(float f) {
    return (short)__bfloat16_as_ushort(__float2bfloat16(f));
}

// ---------------------------------------------------------------------------
// pack_kernel:
//   W1[:128] -> W1p, 32x32x16 B-frag order (zgemm):
//     s = (((kt*4+nt)*64+l)*8+j); k = kt*16+(l>>5)*8+j; n = nt*32+(l&31)
//   W2      -> W2p, 16x16x32 B-frag order (edge kernel):
//     s = (((kt*8+nt)*64+l)*8+j); k = kt*32+(l>>4)*8+j; n = nt*16+(l&15)
// ---------------------------------------------------------------------------
__global__ __launch_bounds__(256) void pack_kernel(
    const float* __restrict__ W1, const float* __restrict__ W2,
    unsigned short* __restrict__ W1p, unsigned short* __restrict__ W2p)
{
    int t = blockIdx.x * 256 + threadIdx.x;
    if (t < 16384) {
        int s = t;
        int j  = s & 7;
        int l  = (s >> 3) & 63;
        int nt = (s >> 9) & 3;
        int kt = (s >> 11) & 7;
        int k = kt * 16 + (l >> 5) * 8 + j;
        int n = nt * 32 + (l & 31);
        W1p[s] = f2bf(W1[k * EF + n]);
    } else if (t < 32768) {
        int s = t - 16384;
        int j  = s & 7;
        int l  = (s >> 3) & 63;
        int nt = (s >> 9) & 7;
        int kt = (s >> 12) & 3;
        int k = kt * 32 + (l >> 4) * 8 + j;
        int n = nt * 16 + (l & 15);
        W2p[s] = f2bf(W2[k * EF + n]);
    }
}

// ---------------------------------------------------------------------------
// zgemm_kernel: Z[p][d] = bf16( b1[d] + sum_k input[p][k] * W1[k][d] )
// (unchanged 32x32x16 structure, verified rounds 2/5)
// ---------------------------------------------------------------------------
__global__ __launch_bounds__(256) void zgemm_kernel(
    const float* __restrict__ input,
    const unsigned short* __restrict__ W1p,
    const float* __restrict__ b1,
    unsigned short* __restrict__ Z,
    int npts, int ntiles)
{
    int l = threadIdx.x & 63;
    int tile = blockIdx.x * 4 + (threadIdx.x >> 6);
    if (tile >= ntiles) return;
    int p0   = tile * 32;
    int r    = l & 31;
    int half = l >> 5;
    int prow = p0 + r;
    if (prow >= npts) prow = npts - 1;      // clamp for ragged tail (reads only)
    const float* Arow = input + (size_t)prow * EF;

    f32x16 acc[4];
#pragma unroll
    for (int nt = 0; nt < 4; ++nt)
#pragma unroll
        for (int i = 0; i < 16; ++i) acc[nt][i] = 0.f;

#pragma unroll
    for (int kt = 0; kt < 8; ++kt) {
        int k0 = kt * 16 + half * 8;
        float4 a0 = *(const float4*)(Arow + k0);
        float4 a1 = *(const float4*)(Arow + k0 + 4);
        short8 a;
        a[0] = f2bf_hw(a0.x); a[1] = f2bf_hw(a0.y);
        a[2] = f2bf_hw(a0.z); a[3] = f2bf_hw(a0.w);
        a[4] = f2bf_hw(a1.x); a[5] = f2bf_hw(a1.y);
        a[6] = f2bf_hw(a1.z); a[7] = f2bf_hw(a1.w);
#pragma unroll
        for (int nt = 0; nt < 4; ++nt) {
            short8 b = *(const short8*)(W1p + ((size_t)((kt * 4 + nt) * 64 + l)) * 8);
            acc[nt] = __builtin_amdgcn_mfma_f32_32x32x16_bf16(a, b, acc[nt], 0, 0, 0);
        }
    }

    int col = l & 31;
#pragma unroll
    for (int nt = 0; nt < 4; ++nt) {
        float bb = b1[nt * 32 + col];
#pragma unroll
        for (int reg = 0; reg < 16; ++reg) {
            int row = (reg & 3) + 8 * (reg >> 2) + 4 * half;
            int p = p0 + row;
            if (p < npts)
                Z[(size_t)p * EF + nt * 32 + col] = f2bf(acc[nt][reg] + bb);
        }
    }
}

// ---------------------------------------------------------------------------
// edge_mfma_kernel (16x16x32): per wave a 16-edge tile (= 2 points).
//   A frag: row = l&15 (edge), k = (l>>4)*8+j (d of h1)
//   h1[e][d] = leaky( Z[idx_e][d] + xyz_e . W1[128:131][d] )
//   h2 = h1 @ W2; out[p][d] = max over the point's 8 edge-rows + b2[d]
//   C/D: col = l&15, row = (l>>4)*4 + reg  (m89-verified layout)
// ---------------------------------------------------------------------------
__global__ __launch_bounds__(256) void edge_mfma_kernel(
    const unsigned short* __restrict__ Z,
    const int* __restrict__ knn_idx,
    const float* __restrict__ knn_xyz,
    const unsigned short* __restrict__ W2p,
    const float* __restrict__ W1,       // xyz rows at +128*EF (f32)
    const float* __restrict__ b2,
    float* __restrict__ out,
    int npts, int nedges, int ntiles)
{
    __shared__ float wlds[3 * EF];      // W1 rows 128..130, f32
    for (int t = threadIdx.x; t < 3 * EF; t += 256)   // FIX: 384 elems, 256 thr
        wlds[t] = W1[EF * EF + t];
    __syncthreads();                    // single barrier, before any exit

    int l = threadIdx.x & 63;
    int tile = blockIdx.x * 4 + (threadIdx.x >> 6);
    if (tile >= ntiles) return;

    int E0 = tile * 16;
    int r  = l & 15;                    // edge row within tile
    int hi = l >> 4;                    // k-group 0..3
    int edge = E0 + r;
    if (edge >= nedges) edge = nedges - 1;   // clamp (reads only)

    int   idx = knn_idx[edge];
    float x = knn_xyz[edge * 3 + 0];
    float y = knn_xyz[edge * 3 + 1];
    float z = knn_xyz[edge * 3 + 2];
    const unsigned short* Zrow = Z + (size_t)idx * EF;

    // hoist all 4 scattered gathers (16B/lane each) before any consumption
    ushort8 zv[4];
#pragma unroll
    for (int kt = 0; kt < 4; ++kt)
        zv[kt] = *(const ushort8*)(Zrow + kt * 32 + hi * 8);

    f32x4 acc[8];
#pragma unroll
    for (int nt = 0; nt < 8; ++nt)
#pragma unroll
        for (int i = 0; i < 4; ++i) acc[nt][i] = 0.f;

#pragma unroll
    for (int kt = 0; kt < 4; ++kt) {
        int d0 = kt * 32 + hi * 8;
        float4 wx0 = *(const float4*)&wlds[0 * EF + d0];
        float4 wx1 = *(const float4*)&wlds[0 * EF + d0 + 4];
        float4 wy0 = *(const float4*)&wlds[1 * EF + d0];
        float4 wy1 = *(const float4*)&wlds[1 * EF + d0 + 4];
        float4 wz0 = *(const float4*)&wlds[2 * EF + d0];
        float4 wz1 = *(const float4*)&wlds[2 * EF + d0 + 4];
        float wxa[8] = {wx0.x, wx0.y, wx0.z, wx0.w, wx1.x, wx1.y, wx1.z, wx1.w};
        float wya[8] = {wy0.x, wy0.y, wy0.z, wy0.w, wy1.x, wy1.y, wy1.z, wy1.w};
        float wza[8] = {wz0.x, wz0.y, wz0.z, wz0.w, wz1.x, wz1.y, wz1.z, wz1.w};

        short8 a;
#pragma unroll
        for (int j = 0; j < 8; ++j) {
            float h = __uint_as_float(((unsigned int)zv[kt][j]) << 16); // bf16->f32
            h = fmaf(x, wxa[j], h);
            h = fmaf(y, wya[j], h);
            h = fmaf(z, wza[j], h);
            h = fmaxf(h, 0.01f * h);    // leaky_relu, exact both signs
            a[j] = f2bf_hw(h);
        }
#pragma unroll
        for (int nt = 0; nt < 8; ++nt) {
            short8 b = *(const short8*)(W2p + ((size_t)((kt * 8 + nt) * 64 + l)) * 8);
            acc[nt] = __builtin_amdgcn_mfma_f32_16x16x32_bf16(a, b, acc[nt], 0, 0, 0);
        }
    }

    // max-pool: lane holds rows hi*4+reg (reg=0..3), col = l&15.
    // point 0 = rows 0..7 (groups 0,1); point 1 = rows 8..15 (groups 2,3).
    int col = l & 15;
#pragma unroll
    for (int nt = 0; nt < 8; ++nt) {
        float m = fmaxf(fmaxf(acc[nt][0], acc[nt][1]),
                        fmaxf(acc[nt][2], acc[nt][3]));
        m = fmaxf(m, __shfl_xor(m, 16));         // combine group pairs (0,1),(2,3)
        if (!(hi & 1)) {
            int p = tile * 2 + (hi >> 1);
            if (p < npts)
                out[(size_t)p * EF + nt * 16 + col] = m + b2[nt * 16 + col];
        }
    }
}

extern "C" void kernel_launch(void* const* d_in, const int* in_sizes, int n_in,
                              void* d_out, int out_size, void* d_ws, size_t ws_size,
                              hipStream_t stream) {
    const float* input   = (const float*)d_in[0];
    const int*   knn_idx = (const int*)  d_in[1];
    const float* knn_xyz = (const float*)d_in[2];
    const float* W1      = (const float*)d_in[3];
    const float* b1      = (const float*)d_in[4];
    const float* W2      = (const float*)d_in[5];
    const float* b2      = (const float*)d_in[6];
    float*       out     = (float*)d_out;

    int npts   = in_sizes[0] / EF;          // 100000
    int nedges = in_sizes[1];               // npts * 8

    // workspace layout
    unsigned short* W1p = (unsigned short*)d_ws;                  // 16384
    unsigned short* W2p = W1p + 16384;                            // 16384
    unsigned short* Z   = (unsigned short*)((char*)d_ws + 65536); // npts*128

    pack_kernel<<<128, 256, 0, stream>>>(W1, W2, W1p, W2p);

    int ztiles = (npts + 31) / 32;
    zgemm_kernel<<<(ztiles + 3) / 4, 256, 0, stream>>>(
        input, W1p, b1, Z, npts, ztiles);

    int etiles = (nedges + 15) / 16;
    edge_mfma_kernel<<<(etiles + 3) / 4, 256, 0, stream>>>(
        Z, knn_idx, knn_xyz, W2p, W1, b2, out, npts, nedges, etiles);
}

// Round 8
// 110.826 us; speedup vs baseline: 5.8293x; 1.1584x over previous
//
#include <hip/hip_runtime.h>
#include <hip/hip_bf16.h>

#define EF 128
#define KNN 8

typedef __attribute__((ext_vector_type(8)))  short          short8;
typedef __attribute__((ext_vector_type(8)))  unsigned short ushort8;
typedef __attribute__((ext_vector_type(4)))  float          f32x4;
typedef __attribute__((ext_vector_type(16))) float          f32x16;

// software round-to-nearest-even f32 -> bf16 bits (cold paths)
static __device__ __forceinline__ unsigned short f2bf(float f) {
    unsigned int x = __float_as_uint(f);
    unsigned int r = x + 0x7fffu + ((x >> 16) & 1u);
    return (unsigned short)(r >> 16);
}
// sanctioned compiler conversion (RNE) for hot paths
static __device__ __forceinline__ short f2bf_hw(float f) {
    return (short)__bfloat16_as_ushort(__float2bfloat16(f));
}

// ---------------------------------------------------------------------------
// pack_kernel:
//   W1[:128] -> W1p, 32x32x16 B-frag order (zgemm):
//     s = (((kt*4+nt)*64+l)*8+j); k = kt*16+(l>>5)*8+j; n = nt*32+(l&31)
//   W2      -> W2p, 16x16x32 B-frag order (edge kernel):
//     s = (((kt*8+nt)*64+l)*8+j); k = kt*32+(l>>4)*8+j; n = nt*16+(l&15)
// ---------------------------------------------------------------------------
__global__ __launch_bounds__(256) void pack_kernel(
    const float* __restrict__ W1, const float* __restrict__ W2,
    unsigned short* __restrict__ W1p, unsigned short* __restrict__ W2p)
{
    int t = blockIdx.x * 256 + threadIdx.x;
    if (t < 16384) {
        int s = t;
        int j  = s & 7;
        int l  = (s >> 3) & 63;
        int nt = (s >> 9) & 3;
        int kt = (s >> 11) & 7;
        int k = kt * 16 + (l >> 5) * 8 + j;
        int n = nt * 32 + (l & 31);
        W1p[s] = f2bf(W1[k * EF + n]);
    } else if (t < 32768) {
        int s = t - 16384;
        int j  = s & 7;
        int l  = (s >> 3) & 63;
        int nt = (s >> 9) & 7;
        int kt = (s >> 12) & 3;
        int k = kt * 32 + (l >> 4) * 8 + j;
        int n = nt * 16 + (l & 15);
        W2p[s] = f2bf(W2[k * EF + n]);
    }
}

// ---------------------------------------------------------------------------
// zgemm_kernel: Z[p][d] = bf16( b1[d] + sum_k input[p][k] * W1[k][d] )
// (unchanged 32x32x16 structure, verified rounds 2/5/7)
// ---------------------------------------------------------------------------
__global__ __launch_bounds__(256) void zgemm_kernel(
    const float* __restrict__ input,
    const unsigned short* __restrict__ W1p,
    const float* __restrict__ b1,
    unsigned short* __restrict__ Z,
    int npts, int ntiles)
{
    int l = threadIdx.x & 63;
    int tile = blockIdx.x * 4 + (threadIdx.x >> 6);
    if (tile >= ntiles) return;
    int p0   = tile * 32;
    int r    = l & 31;
    int half = l >> 5;
    int prow = p0 + r;
    if (prow >= npts) prow = npts - 1;      // clamp for ragged tail (reads only)
    const float* Arow = input + (size_t)prow * EF;

    f32x16 acc[4];
#pragma unroll
    for (int nt = 0; nt < 4; ++nt)
#pragma unroll
        for (int i = 0; i < 16; ++i) acc[nt][i] = 0.f;

#pragma unroll
    for (int kt = 0; kt < 8; ++kt) {
        int k0 = kt * 16 + half * 8;
        float4 a0 = *(const float4*)(Arow + k0);
        float4 a1 = *(const float4*)(Arow + k0 + 4);
        short8 a;
        a[0] = f2bf_hw(a0.x); a[1] = f2bf_hw(a0.y);
        a[2] = f2bf_hw(a0.z); a[3] = f2bf_hw(a0.w);
        a[4] = f2bf_hw(a1.x); a[5] = f2bf_hw(a1.y);
        a[6] = f2bf_hw(a1.z); a[7] = f2bf_hw(a1.w);
#pragma unroll
        for (int nt = 0; nt < 4; ++nt) {
            short8 b = *(const short8*)(W1p + ((size_t)((kt * 4 + nt) * 64 + l)) * 8);
            acc[nt] = __builtin_amdgcn_mfma_f32_32x32x16_bf16(a, b, acc[nt], 0, 0, 0);
        }
    }

    int col = l & 31;
#pragma unroll
    for (int nt = 0; nt < 4; ++nt) {
        float bb = b1[nt * 32 + col];
#pragma unroll
        for (int reg = 0; reg < 16; ++reg) {
            int row = (reg & 3) + 8 * (reg >> 2) + 4 * half;
            int p = p0 + row;
            if (p < npts)
                Z[(size_t)p * EF + nt * 32 + col] = f2bf(acc[nt][reg] + bb);
        }
    }
}

// ---------------------------------------------------------------------------
// edge_mfma_kernel (16x16x32): per wave a 16-edge tile (= 2 points).
// W2 fragments staged in LDS once per block (32 KB) -> ds_read_b128;
// per-wave VMEM reduced to the 4 Z-gathers + idx/xyz, freeing L1/TA.
// ---------------------------------------------------------------------------
__global__ __launch_bounds__(256) void edge_mfma_kernel(
    const unsigned short* __restrict__ Z,
    const int* __restrict__ knn_idx,
    const float* __restrict__ knn_xyz,
    const unsigned short* __restrict__ W2p,
    const float* __restrict__ W1,       // xyz rows at +128*EF (f32)
    const float* __restrict__ b2,
    float* __restrict__ out,
    int npts, int nedges, int ntiles)
{
    __shared__ short8 w2lds[2048];      // 32 KB: full packed W2, frag order
    __shared__ float  wlds[3 * EF];     // W1 rows 128..130, f32

    int l    = threadIdx.x & 63;
    int tile = blockIdx.x * 4 + (threadIdx.x >> 6);
    bool active = tile < ntiles;

    int E0 = tile * 16;
    int r  = l & 15;                    // edge row within tile
    int hi = l >> 4;                    // k-group 0..3
    int edge = active ? (E0 + r) : 0;
    if (edge >= nedges) edge = nedges - 1;   // clamp (reads only)

    // ---- issue scattered gathers FIRST (latency hides under LDS staging) --
    int   idx = knn_idx[edge];
    float x = knn_xyz[edge * 3 + 0];
    float y = knn_xyz[edge * 3 + 1];
    float z = knn_xyz[edge * 3 + 2];
    const unsigned short* Zrow = Z + (size_t)idx * EF;
    ushort8 zv[4];
#pragma unroll
    for (int kt = 0; kt < 4; ++kt)
        zv[kt] = *(const ushort8*)(Zrow + kt * 32 + hi * 8);

    // ---- stage W2 fragments + xyz weights into LDS ------------------------
    {
        const short8* W2v = (const short8*)W2p;
#pragma unroll
        for (int i = threadIdx.x; i < 2048; i += 256)
            w2lds[i] = W2v[i];
        for (int t = threadIdx.x; t < 3 * EF; t += 256)
            wlds[t] = W1[EF * EF + t];
    }
    __syncthreads();
    if (!active) return;

    f32x4 acc[8];
#pragma unroll
    for (int nt = 0; nt < 8; ++nt)
#pragma unroll
        for (int i = 0; i < 4; ++i) acc[nt][i] = 0.f;

#pragma unroll
    for (int kt = 0; kt < 4; ++kt) {
        int d0 = kt * 32 + hi * 8;
        float4 wx0 = *(const float4*)&wlds[0 * EF + d0];
        float4 wx1 = *(const float4*)&wlds[0 * EF + d0 + 4];
        float4 wy0 = *(const float4*)&wlds[1 * EF + d0];
        float4 wy1 = *(const float4*)&wlds[1 * EF + d0 + 4];
        float4 wz0 = *(const float4*)&wlds[2 * EF + d0];
        float4 wz1 = *(const float4*)&wlds[2 * EF + d0 + 4];
        float wxa[8] = {wx0.x, wx0.y, wx0.z, wx0.w, wx1.x, wx1.y, wx1.z, wx1.w};
        float wya[8] = {wy0.x, wy0.y, wy0.z, wy0.w, wy1.x, wy1.y, wy1.z, wy1.w};
        float wza[8] = {wz0.x, wz0.y, wz0.z, wz0.w, wz1.x, wz1.y, wz1.z, wz1.w};

        short8 a;
#pragma unroll
        for (int j = 0; j < 8; ++j) {
            float h = __uint_as_float(((unsigned int)zv[kt][j]) << 16); // bf16->f32
            h = fmaf(x, wxa[j], h);
            h = fmaf(y, wya[j], h);
            h = fmaf(z, wza[j], h);
            h = fmaxf(h, 0.01f * h);    // leaky_relu, exact both signs
            a[j] = f2bf_hw(h);
        }
#pragma unroll
        for (int nt = 0; nt < 8; ++nt) {
            short8 b = w2lds[(kt * 8 + nt) * 64 + l];   // ds_read_b128
            acc[nt] = __builtin_amdgcn_mfma_f32_16x16x32_bf16(a, b, acc[nt], 0, 0, 0);
        }
    }

    // max-pool: lane holds rows hi*4+reg (reg=0..3), col = l&15.
    int col = l & 15;
#pragma unroll
    for (int nt = 0; nt < 8; ++nt) {
        float m = fmaxf(fmaxf(acc[nt][0], acc[nt][1]),
                        fmaxf(acc[nt][2], acc[nt][3]));
        m = fmaxf(m, __shfl_xor(m, 16));         // combine group pairs (0,1),(2,3)
        if (!(hi & 1)) {
            int p = tile * 2 + (hi >> 1);
            if (p < npts)
                out[(size_t)p * EF + nt * 16 + col] = m + b2[nt * 16 + col];
        }
    }
}

extern "C" void kernel_launch(void* const* d_in, const int* in_sizes, int n_in,
                              void* d_out, int out_size, void* d_ws, size_t ws_size,
                              hipStream_t stream) {
    const float* input   = (const float*)d_in[0];
    const int*   knn_idx = (const int*)  d_in[1];
    const float* knn_xyz = (const float*)d_in[2];
    const float* W1      = (const float*)d_in[3];
    const float* b1      = (const float*)d_in[4];
    const float* W2      = (const float*)d_in[5];
    const float* b2      = (const float*)d_in[6];
    float*       out     = (float*)d_out;

    int npts   = in_sizes[0] / EF;          // 100000
    int nedges = in_sizes[1];               // npts * 8

    // workspace layout
    unsigned short* W1p = (unsigned short*)d_ws;                  // 16384
    unsigned short* W2p = W1p + 16384;                            // 16384
    unsigned short* Z   = (unsigned short*)((char*)d_ws + 65536); // npts*128

    pack_kernel<<<128, 256, 0, stream>>>(W1, W2, W1p, W2p);

    int ztiles = (npts + 31) / 32;
    zgemm_kernel<<<(ztiles + 3) / 4, 256, 0, stream>>>(
        input, W1p, b1, Z, npts, ztiles);

    int etiles = (nedges + 15) / 16;
    edge_mfma_kernel<<<(etiles + 3) / 4, 256, 0, stream>>>(
        Z, knn_idx, knn_xyz, W2p, W1, b2, out, npts, nedges, etiles);
}

// Round 9
// 91.963 us; speedup vs baseline: 7.0249x; 1.2051x over previous
//
#include <hip/hip_runtime.h>
#include <hip/hip_bf16.h>

#define EF 128
#define KNN 8

typedef __attribute__((ext_vector_type(8)))  short          short8;
typedef __attribute__((ext_vector_type(8)))  unsigned short ushort8;
typedef __attribute__((ext_vector_type(4)))  float          f32x4;
typedef __attribute__((ext_vector_type(16))) float          f32x16;

// software round-to-nearest-even f32 -> bf16 bits (cold paths)
static __device__ __forceinline__ unsigned short f2bf(float f) {
    unsigned int x = __float_as_uint(f);
    unsigned int r = x + 0x7fffu + ((x >> 16) & 1u);
    return (unsigned short)(r >> 16);
}
// sanctioned compiler conversion (RNE) for hot paths
static __device__ __forceinline__ short f2bf_hw(float f) {
    return (short)__bfloat16_as_ushort(__float2bfloat16(f));
}

// ---------------------------------------------------------------------------
// pack_kernel:
//   W1[:128] -> W1p, 32x32x16 B-frag order (zgemm):
//     s = (((kt*4+nt)*64+l)*8+j); k = kt*16+(l>>5)*8+j; n = nt*32+(l&31)
//   W2      -> W2p, 16x16x32 B-frag order (edge kernel):
//     s = (((kt*8+nt)*64+l)*8+j); k = kt*32+(l>>4)*8+j; n = nt*16+(l&15)
// ---------------------------------------------------------------------------
__global__ __launch_bounds__(256) void pack_kernel(
    const float* __restrict__ W1, const float* __restrict__ W2,
    unsigned short* __restrict__ W1p, unsigned short* __restrict__ W2p)
{
    int t = blockIdx.x * 256 + threadIdx.x;
    if (t < 16384) {
        int s = t;
        int j  = s & 7;
        int l  = (s >> 3) & 63;
        int nt = (s >> 9) & 3;
        int kt = (s >> 11) & 7;
        int k = kt * 16 + (l >> 5) * 8 + j;
        int n = nt * 32 + (l & 31);
        W1p[s] = f2bf(W1[k * EF + n]);
    } else if (t < 32768) {
        int s = t - 16384;
        int j  = s & 7;
        int l  = (s >> 3) & 63;
        int nt = (s >> 9) & 7;
        int kt = (s >> 12) & 3;
        int k = kt * 32 + (l >> 4) * 8 + j;
        int n = nt * 16 + (l & 15);
        W2p[s] = f2bf(W2[k * EF + n]);
    }
}

// ---------------------------------------------------------------------------
// zgemm_kernel: Z[p][d] = bf16( b1[d] + sum_k input[p][k] * W1[k][d] )
// (unchanged 32x32x16 structure, verified rounds 2/5/7/8)
// ---------------------------------------------------------------------------
__global__ __launch_bounds__(256) void zgemm_kernel(
    const float* __restrict__ input,
    const unsigned short* __restrict__ W1p,
    const float* __restrict__ b1,
    unsigned short* __restrict__ Z,
    int npts, int ntiles)
{
    int l = threadIdx.x & 63;
    int tile = blockIdx.x * 4 + (threadIdx.x >> 6);
    if (tile >= ntiles) return;
    int p0   = tile * 32;
    int r    = l & 31;
    int half = l >> 5;
    int prow = p0 + r;
    if (prow >= npts) prow = npts - 1;      // clamp for ragged tail (reads only)
    const float* Arow = input + (size_t)prow * EF;

    f32x16 acc[4];
#pragma unroll
    for (int nt = 0; nt < 4; ++nt)
#pragma unroll
        for (int i = 0; i < 16; ++i) acc[nt][i] = 0.f;

#pragma unroll
    for (int kt = 0; kt < 8; ++kt) {
        int k0 = kt * 16 + half * 8;
        float4 a0 = *(const float4*)(Arow + k0);
        float4 a1 = *(const float4*)(Arow + k0 + 4);
        short8 a;
        a[0] = f2bf_hw(a0.x); a[1] = f2bf_hw(a0.y);
        a[2] = f2bf_hw(a0.z); a[3] = f2bf_hw(a0.w);
        a[4] = f2bf_hw(a1.x); a[5] = f2bf_hw(a1.y);
        a[6] = f2bf_hw(a1.z); a[7] = f2bf_hw(a1.w);
#pragma unroll
        for (int nt = 0; nt < 4; ++nt) {
            short8 b = *(const short8*)(W1p + ((size_t)((kt * 4 + nt) * 64 + l)) * 8);
            acc[nt] = __builtin_amdgcn_mfma_f32_32x32x16_bf16(a, b, acc[nt], 0, 0, 0);
        }
    }

    int col = l & 31;
#pragma unroll
    for (int nt = 0; nt < 4; ++nt) {
        float bb = b1[nt * 32 + col];
#pragma unroll
        for (int reg = 0; reg < 16; ++reg) {
            int row = (reg & 3) + 8 * (reg >> 2) + 4 * half;
            int p = p0 + row;
            if (p < npts)
                Z[(size_t)p * EF + nt * 32 + col] = f2bf(acc[nt][reg] + bb);
        }
    }
}

// ---------------------------------------------------------------------------
// edge_mfma_kernel (16x16x32): per wave a 16-edge tile (= 2 points).
// 512-thread blocks (8 waves) share one 32 KB W2 LDS copy -> 100% occupancy
// cap (4 blocks/CU) and halved W2 staging traffic.
// ---------------------------------------------------------------------------
__global__ __launch_bounds__(512) void edge_mfma_kernel(
    const unsigned short* __restrict__ Z,
    const int* __restrict__ knn_idx,
    const float* __restrict__ knn_xyz,
    const unsigned short* __restrict__ W2p,
    const float* __restrict__ W1,       // xyz rows at +128*EF (f32)
    const float* __restrict__ b2,
    float* __restrict__ out,
    int npts, int nedges, int ntiles)
{
    __shared__ short8 w2lds[2048];      // 32 KB: full packed W2, frag order
    __shared__ float  wlds[3 * EF];     // W1 rows 128..130, f32

    int l    = threadIdx.x & 63;
    int tile = blockIdx.x * 8 + (threadIdx.x >> 6);
    bool active = tile < ntiles;

    int E0 = tile * 16;
    int r  = l & 15;                    // edge row within tile
    int hi = l >> 4;                    // k-group 0..3
    int edge = active ? (E0 + r) : 0;
    if (edge >= nedges) edge = nedges - 1;   // clamp (reads only)

    // ---- issue scattered gathers FIRST (latency hides under LDS staging) --
    int   idx = knn_idx[edge];
    float x = knn_xyz[edge * 3 + 0];
    float y = knn_xyz[edge * 3 + 1];
    float z = knn_xyz[edge * 3 + 2];
    const unsigned short* Zrow = Z + (size_t)idx * EF;
    ushort8 zv[4];
#pragma unroll
    for (int kt = 0; kt < 4; ++kt)
        zv[kt] = *(const ushort8*)(Zrow + kt * 32 + hi * 8);

    // ---- stage W2 fragments + xyz weights into LDS ------------------------
    {
        const short8* W2v = (const short8*)W2p;
#pragma unroll
        for (int i = threadIdx.x; i < 2048; i += 512)
            w2lds[i] = W2v[i];
        for (int t = threadIdx.x; t < 3 * EF; t += 512)
            wlds[t] = W1[EF * EF + t];
    }
    __syncthreads();
    if (!active) return;

    f32x4 acc[8];
#pragma unroll
    for (int nt = 0; nt < 8; ++nt)
#pragma unroll
        for (int i = 0; i < 4; ++i) acc[nt][i] = 0.f;

#pragma unroll
    for (int kt = 0; kt < 4; ++kt) {
        int d0 = kt * 32 + hi * 8;
        float4 wx0 = *(const float4*)&wlds[0 * EF + d0];
        float4 wx1 = *(const float4*)&wlds[0 * EF + d0 + 4];
        float4 wy0 = *(const float4*)&wlds[1 * EF + d0];
        float4 wy1 = *(const float4*)&wlds[1 * EF + d0 + 4];
        float4 wz0 = *(const float4*)&wlds[2 * EF + d0];
        float4 wz1 = *(const float4*)&wlds[2 * EF + d0 + 4];
        float wxa[8] = {wx0.x, wx0.y, wx0.z, wx0.w, wx1.x, wx1.y, wx1.z, wx1.w};
        float wya[8] = {wy0.x, wy0.y, wy0.z, wy0.w, wy1.x, wy1.y, wy1.z, wy1.w};
        float wza[8] = {wz0.x, wz0.y, wz0.z, wz0.w, wz1.x, wz1.y, wz1.z, wz1.w};

        short8 a;
#pragma unroll
        for (int j = 0; j < 8; ++j) {
            float h = __uint_as_float(((unsigned int)zv[kt][j]) << 16); // bf16->f32
            h = fmaf(x, wxa[j], h);
            h = fmaf(y, wya[j], h);
            h = fmaf(z, wza[j], h);
            h = fmaxf(h, 0.01f * h);    // leaky_relu, exact both signs
            a[j] = f2bf_hw(h);
        }
#pragma unroll
        for (int nt = 0; nt < 8; ++nt) {
            short8 b = w2lds[(kt * 8 + nt) * 64 + l];   // ds_read_b128
            acc[nt] = __builtin_amdgcn_mfma_f32_16x16x32_bf16(a, b, acc[nt], 0, 0, 0);
        }
    }

    // max-pool: lane holds rows hi*4+reg (reg=0..3), col = l&15.
    int col = l & 15;
#pragma unroll
    for (int nt = 0; nt < 8; ++nt) {
        float m = fmaxf(fmaxf(acc[nt][0], acc[nt][1]),
                        fmaxf(acc[nt][2], acc[nt][3]));
        m = fmaxf(m, __shfl_xor(m, 16));         // combine group pairs (0,1),(2,3)
        if (!(hi & 1)) {
            int p = tile * 2 + (hi >> 1);
            if (p < npts)
                out[(size_t)p * EF + nt * 16 + col] = m + b2[nt * 16 + col];
        }
    }
}

extern "C" void kernel_launch(void* const* d_in, const int* in_sizes, int n_in,
                              void* d_out, int out_size, void* d_ws, size_t ws_size,
                              hipStream_t stream) {
    const float* input   = (const float*)d_in[0];
    const int*   knn_idx = (const int*)  d_in[1];
    const float* knn_xyz = (const float*)d_in[2];
    const float* W1      = (const float*)d_in[3];
    const float* b1      = (const float*)d_in[4];
    const float* W2      = (const float*)d_in[5];
    const float* b2      = (const float*)d_in[6];
    float*       out     = (float*)d_out;

    int npts   = in_sizes[0] / EF;          // 100000
    int nedges = in_sizes[1];               // npts * 8

    // workspace layout
    unsigned short* W1p = (unsigned short*)d_ws;                  // 16384
    unsigned short* W2p = W1p + 16384;                            // 16384
    unsigned short* Z   = (unsigned short*)((char*)d_ws + 65536); // npts*128

    pack_kernel<<<128, 256, 0, stream>>>(W1, W2, W1p, W2p);

    int ztiles = (npts + 31) / 32;
    zgemm_kernel<<<(ztiles + 3) / 4, 256, 0, stream>>>(
        input, W1p, b1, Z, npts, ztiles);

    int etiles = (nedges + 15) / 16;
    edge_mfma_kernel<<<(etiles + 7) / 8, 512, 0, stream>>>(
        Z, knn_idx, knn_xyz, W2p, W1, b2, out, npts, nedges, etiles);
}